// Round 8
// baseline (271.649 us; speedup 1.0000x reference)
//
#include <hip/hip_runtime.h>
#include <hip/hip_bf16.h>
#include <math.h>

// ---------------------------------------------------------------------------
// Reduction (proven r0): gated attention is identically zero => model ==
// two residual FFN blocks:
//   p_out = p_h + gelu(LN(p_h)@w1[1]+b1[1])@w2[1]+b2[1]
//   l_out = l_h + gelu(LN(l_h)@w1[0]+b1[0])@w2[0]+b2[0]
// r8: GEMM1 = true 256x256 8-phase template: quadrant = 2Mfrag x 4Nfrag x
// K64 (B LDS-read ONCE per K-tile into regs -> 24 ds_reads/K-tile not 96),
// per-half staging, vmcnt(6)=3 half-tiles in flight (ledger verified),
// wave rows remapped so quadrant q reads only A-half q>>1 (half-overwrite
// safety). GEMM2 = r7-proven gemm97 (multi-block TLP, 795 TF).
// ---------------------------------------------------------------------------

#define DIM 1024
#define DFF 4096
#define MP 8192
#define ML 2048
#define MT (MP + ML)  // 10240 rows, P first then L

typedef __bf16 bf16x8 __attribute__((ext_vector_type(8)));
typedef float f32x4 __attribute__((ext_vector_type(4)));
using bf16 = __hip_bfloat16;

// ---------------- transpose + cast: f32 [R][C] -> bf16 [C][R] ---------------
__global__ void transpose_cast(const float* __restrict__ in, bf16* __restrict__ out,
                               int R, int C) {
  __shared__ float tile[32][33];
  int c0 = blockIdx.x * 32;
  int r0 = blockIdx.y * 32;
  int tc = threadIdx.x & 31;
  int tr = threadIdx.x >> 5;
#pragma unroll
  for (int i = 0; i < 4; i++)
    tile[tr + i * 8][tc] = in[(size_t)(r0 + tr + i * 8) * C + c0 + tc];
  __syncthreads();
#pragma unroll
  for (int i = 0; i < 4; i++)
    out[(size_t)(c0 + tr + i * 8) * R + r0 + tc] = __float2bfloat16(tile[tc][tr + i * 8]);
}

// ---------------- LayerNorm rows: f32 [rows][1024] -> bf16 ------------------
__global__ void ln_rows(const float* __restrict__ x, const float* __restrict__ sc,
                        const float* __restrict__ bi, bf16* __restrict__ y) {
  int row = blockIdx.x;
  int t = threadIdx.x;
  float4 v = ((const float4*)(x + (size_t)row * DIM))[t];
  float s = v.x + v.y + v.z + v.w;
#pragma unroll
  for (int o = 32; o >= 1; o >>= 1) s += __shfl_down(s, o);
  __shared__ float red[8];
  int lane = t & 63, w = t >> 6;
  if (lane == 0) red[w] = s;
  __syncthreads();
  float mean = (red[0] + red[1] + red[2] + red[3]) * (1.0f / DIM);
  float dx = v.x - mean, dy = v.y - mean, dz = v.z - mean, dw = v.w - mean;
  float ss = dx * dx + dy * dy + dz * dz + dw * dw;
#pragma unroll
  for (int o = 32; o >= 1; o >>= 1) ss += __shfl_down(ss, o);
  if (lane == 0) red[4 + w] = ss;
  __syncthreads();
  float var = (red[4] + red[5] + red[6] + red[7]) * (1.0f / DIM);
  float rstd = rsqrtf(var + 1e-5f);
  float4 scv = ((const float4*)sc)[t];
  float4 biv = ((const float4*)bi)[t];
  bf16 o4[4];
  o4[0] = __float2bfloat16(dx * rstd * scv.x + biv.x);
  o4[1] = __float2bfloat16(dy * rstd * scv.y + biv.y);
  o4[2] = __float2bfloat16(dz * rstd * scv.z + biv.z);
  o4[3] = __float2bfloat16(dw * rstd * scv.w + biv.w);
  *(short4*)(y + (size_t)row * DIM + t * 4) = *(short4*)o4;
}

#define BAR() __builtin_amdgcn_s_barrier()
#define LGKM0() asm volatile("s_waitcnt lgkmcnt(0)" ::: "memory")
#define LGKM8() asm volatile("s_waitcnt lgkmcnt(8)" ::: "memory")
#define VMC(n) asm volatile("s_waitcnt vmcnt(" #n ")" ::: "memory")
#define MFMA_ __builtin_amdgcn_mfma_f32_16x16x32_bf16

// ================= 256x256 BK=64 8-phase template (GEMM1) ===================
// LDS (elements): dbuf d*32768 + { Bh0:0, Bh1:8192, Ah0:16384, Ah1:24576 }.
// Each half = [128 rows][64 k] bf16, granule-XOR swizzle phys_g = g^(row&7)
// (r7-proven conflict-free). Tile t -> dbuf t&1.
// Wave rows remapped: wave wm owns rows {wm*64+[0,64)} u {128+wm*64+[0,64)};
// quadrant q (phases 1-4 of a tile) = frags mf{2q,2q+1} -> reads ONLY
// A-half (q>>1): Ah0 free after phase 2, Ah1 after phase 4.
// Staging per phase (ledger, steady state; outstanding loads in brackets):
//  p1: stage t+1.Ah1 [8]   p2: t+2.Bh0 [10]  p3: t+2.Bh1 [12]
//  p4: t+2.Ah0 [14] VMC(6) -> drains ALL of t+1 (8 oldest)
//  p5: t+2.Ah1 [8]   p6: t+3.Bh0 [10]  p7: t+3.Bh1 [12]
//  p8: t+3.Ah0 [14] VMC(6) -> drains all of t+2.
// B-frags (8 x bf16x8) LDS-read once per K-tile (12-read phase + lgkmcnt(8)),
// A-frags (4) per phase => 24 ds_read_b128 per K-tile per wave.

#define STG(ptrS, hh, tt, slotBase)                                                 \
  do {                                                                              \
    __builtin_amdgcn_global_load_lds(                                               \
        (const __attribute__((address_space(1))) void*)((ptrS) + (2 * (hh)) * k64 + (tt) * 64), \
        (__attribute__((address_space(3))) void*)(smem + (slotBase) + (hh) * 8192 + wv512), 16, 0, 0); \
    __builtin_amdgcn_global_load_lds(                                               \
        (const __attribute__((address_space(1))) void*)((ptrS) + (2 * (hh) + 1) * k64 + (tt) * 64), \
        (__attribute__((address_space(3))) void*)(smem + (slotBase) + (hh) * 8192 + 4096 + wv512), 16, 0, 0); \
  } while (0)

#define RDA_(q, dd)                                                                 \
  {                                                                                 \
    const bf16* sA_ = smem + (dd) * 32768 + 16384 + ((q) >> 1) * 8192 + ((q) & 1) * 2048 + rowA; \
    a00 = *(const bf16x8*)(sA_ + og0);                                              \
    a01 = *(const bf16x8*)(sA_ + og1);                                              \
    a10 = *(const bf16x8*)(sA_ + 1024 + og0);                                       \
    a11 = *(const bf16x8*)(sA_ + 1024 + og1);                                       \
  }

#define RDB_(dd)                                                                    \
  {                                                                                 \
    const bf16* sB_ = smem + (dd) * 32768 + bSlot + rowB;                           \
    _Pragma("unroll") for (int nf = 0; nf < 4; nf++) {                              \
      b0[nf] = *(const bf16x8*)(sB_ + nf * 1024 + og0);                             \
      b1[nf] = *(const bf16x8*)(sB_ + nf * 1024 + og1);                             \
    }                                                                               \
  }

#define MMQ_(q)                                                                     \
  __builtin_amdgcn_s_setprio(1);                                                    \
  _Pragma("unroll") for (int nf = 0; nf < 4; nf++) {                                \
    acc[(q) * 2 + 0][nf] = MFMA_(a00, b0[nf], acc[(q) * 2 + 0][nf], 0, 0, 0);       \
    acc[(q) * 2 + 0][nf] = MFMA_(a01, b1[nf], acc[(q) * 2 + 0][nf], 0, 0, 0);       \
    acc[(q) * 2 + 1][nf] = MFMA_(a10, b0[nf], acc[(q) * 2 + 1][nf], 0, 0, 0);       \
    acc[(q) * 2 + 1][nf] = MFMA_(a11, b1[nf], acc[(q) * 2 + 1][nf], 0, 0, 0);       \
  }                                                                                 \
  __builtin_amdgcn_s_setprio(0);

template <int EPI>  // 0: gelu -> bf16 h ; 1: +bias +resid -> f32 out
__global__ __launch_bounds__(512, 2) void gemm256(
    const bf16* __restrict__ A, const bf16* __restrict__ B0, const bf16* __restrict__ B1,
    const float* __restrict__ bias0, const float* __restrict__ bias1,
    const float* __restrict__ res0, const float* __restrict__ res1,
    void* __restrict__ outv, int N, int K, int nRow) {
  __shared__ alignas(16) bf16 smem[65536];  // 128 KiB
  const int tid = threadIdx.x;
  const int lane = tid & 63;
  const int wave = tid >> 6;  // 0..7
  const int wm = wave >> 2;   // 0..1
  const int wn = wave & 3;    // 0..3
  const int NT = K >> 6;      // BK=64; NT even, >= 4

  const int nwg = gridDim.x;
  const int swz = (blockIdx.x & 7) * (nwg >> 3) + (blockIdx.x >> 3);
  const int m0 = (swz % nRow) << 8;  // m-fastest: B-panel reuse per XCD chunk
  const int n0 = (swz / nRow) << 8;

  const bool isP = (m0 < MP);
  const bf16* Bt = isP ? B1 : B0;
  const float* bias = isP ? bias1 : bias0;

  // staging map: dest elem = slot + tid*8 (linear); row = tid>>3 within
  // 64-row instr-block; logical granule pre-swizzled into global col.
  const int srloc = tid >> 3;
  const int sg = (tid & 7) ^ (srloc & 7);
  const bf16* aS = A + (size_t)(m0 + srloc) * K + sg * 8;
  const bf16* bS = Bt + (size_t)(n0 + srloc) * K + sg * 8;
  const size_t k64 = (size_t)64 * K;
  const int wv512 = wave << 9;

  // read map (r7-proven): og = ((ksub*4+G) ^ (lr&7)) * 8
  const int lr = lane & 15;
  const int G = lane >> 4;
  const int x7 = lr & 7;
  const int og0 = (G ^ x7) << 3;
  const int og1 = ((4 + G) ^ x7) << 3;
  const int rowA = (wm * 64 + lr) * 64;        // elems within A-half
  const int rowB = ((wn & 1) * 64 + lr) * 64;  // elems within B-half
  const int bSlot = (wn >> 1) * 8192;

  f32x4 acc[8][4] = {};
  bf16x8 b0[4], b1[4];

  // prologue: tile0 all 4 halves -> dbuf0; tile1 Bh0,Bh1,Ah0 -> dbuf1.
  // 14 loads; VMC(6) drains tile0 fully, leaves tile1's 3 halves in flight.
  STG(bS, 0, 0, 0);     STG(bS, 1, 0, 0);
  STG(aS, 0, 0, 16384); STG(aS, 1, 0, 16384);
  STG(bS, 0, 1, 32768); STG(bS, 1, 1, 32768);
  STG(aS, 0, 1, 49152);
  VMC(6);
  BAR();

  for (int t = 0; t < NT; t += 2) {
    const bool st = (t + 2 < NT);
    bf16x8 a00, a01, a10, a11;
    // ---- tile t (dbuf0) ----
    RDB_(0); RDA_(0, 0);
    STG(aS, 1, t + 1, 49152);  // t+1.Ah1 -> dbuf1
    LGKM8();
    BAR(); LGKM0(); MMQ_(0); BAR();
    RDA_(1, 0);
    if (st) STG(bS, 0, t + 2, 0);
    BAR(); LGKM0(); MMQ_(1); BAR();
    RDA_(2, 0);
    if (st) STG(bS, 1, t + 2, 0);
    BAR(); LGKM0(); MMQ_(2); BAR();
    RDA_(3, 0);
    if (st) { STG(aS, 0, t + 2, 16384); VMC(6); } else { VMC(0); }
    BAR(); LGKM0(); MMQ_(3); BAR();
    // ---- tile t+1 (dbuf1) ----
    RDB_(1); RDA_(0, 1);
    if (st) STG(aS, 1, t + 2, 16384);  // t+2.Ah1 -> dbuf0
    LGKM8();
    BAR(); LGKM0(); MMQ_(0); BAR();
    RDA_(1, 1);
    if (st) STG(bS, 0, t + 3, 32768);
    BAR(); LGKM0(); MMQ_(1); BAR();
    RDA_(2, 1);
    if (st) STG(bS, 1, t + 3, 32768);
    BAR(); LGKM0(); MMQ_(2); BAR();
    RDA_(3, 1);
    if (st) { STG(aS, 0, t + 3, 49152); VMC(6); } else { VMC(0); }
    BAR(); LGKM0(); MMQ_(3); BAR();
  }

  // ---- epilogue (LDS-bounce, r5-verified pattern). Row remap:
  // grow(am) = (am>>2)*128 + wm*64 + ((am>>1)&1)*32 + (am&1)*16 + lr4 + q
  const int lr4 = (lane >> 4) << 2;
  const int lc = lane & 15;
  if (EPI == 0) {
    bf16* hs = smem;  // [256][256] bf16
#pragma unroll
    for (int nf = 0; nf < 4; nf++) {
      int col = wn * 64 + nf * 16 + lc;
      float bb = bias[n0 + col];
#pragma unroll
      for (int am = 0; am < 8; am++) {
        int lrow = (am >> 2) * 128 + wm * 64 + ((am >> 1) & 1) * 32 + (am & 1) * 16 + lr4;
#pragma unroll
        for (int q = 0; q < 4; q++) {
          float v = acc[am][nf][q] + bb;
          float u2 = 0.7978845608028654f * (v + 0.044715f * v * v * v);
          float th = 1.0f - 2.0f / (__expf(2.0f * u2) + 1.0f);  // tanh
          hs[(lrow + q) * 256 + col] = __float2bfloat16(0.5f * v * (1.0f + th));
        }
      }
    }
    BAR();
    bf16* hO = (bf16*)outv;
#pragma unroll
    for (int it = 0; it < 16; it++) {
      int gr = tid + it * 512;
      int row = gr >> 5;
      int col = (gr & 31) * 8;
      *(bf16x8*)(hO + (size_t)(m0 + row) * N + n0 + col) = *(const bf16x8*)(hs + gr * 8);
    }
  } else {
    float* o = (float*)outv;
    const float* res = isP ? (res1 + (size_t)m0 * N) : (res0 + (size_t)(m0 - MP) * N);
    float* fs = (float*)smem;  // [128][256] f32 per half-pass
#pragma unroll
    for (int hp = 0; hp < 2; hp++) {
#pragma unroll
      for (int j = 0; j < 4; j++) {
        int am = hp * 4 + j;
        int lrow = wm * 64 + ((am >> 1) & 1) * 32 + (am & 1) * 16 + lr4;
#pragma unroll
        for (int nf = 0; nf < 4; nf++) {
          int col = wn * 64 + nf * 16 + lc;
          float bb = bias[n0 + col];
#pragma unroll
          for (int q = 0; q < 4; q++) fs[(lrow + q) * 256 + col] = acc[am][nf][q] + bb;
        }
      }
      BAR();
#pragma unroll
      for (int it = 0; it < 16; it++) {
        int gr = tid + it * 512;
        int row = gr >> 6;
        int col = (gr & 63) * 4;
        size_t goff = (size_t)(hp * 128 + row) * N + n0 + col;
        float4 v = *(const float4*)(fs + gr * 4);
        float4 rr = *(const float4*)(res + goff);
        v.x += rr.x; v.y += rr.y; v.z += rr.z; v.w += rr.w;
        *(float4*)(o + (size_t)m0 * N + goff) = v;
      }
      BAR();
    }
  }
}

// ================= 128x128 m97-style GEMM (GEMM2, r7-proven) ================
#define GLOAD(gp, ldsElem)                                                          \
  __builtin_amdgcn_global_load_lds(                                                 \
      (const __attribute__((address_space(1))) void*)(gp),                          \
      (__attribute__((address_space(3))) void*)(ldsElem), 16, 0, 0)

template <int EPI>
__global__ __launch_bounds__(256, 3) void gemm97(
    const bf16* __restrict__ A, const bf16* __restrict__ B0, const bf16* __restrict__ B1,
    const float* __restrict__ bias0, const float* __restrict__ bias1,
    const float* __restrict__ res0, const float* __restrict__ res1,
    void* __restrict__ outv, int N, int K, int nCol) {
  __shared__ alignas(16) bf16 smem[16384];
  const int tid = threadIdx.x;
  const int lane = tid & 63;
  const int wave = tid >> 6;

  const int nwg = gridDim.x;
  const int swz = (blockIdx.x & 7) * (nwg >> 3) + (blockIdx.x >> 3);
  const int m0 = (swz / nCol) << 7;
  const int n0 = (swz % nCol) << 7;

  const bool isP = (m0 < MP);
  const bf16* Bt = isP ? B1 : B0;
  const float* bias = isP ? bias1 : bias0;

  const int srow = wave * 32 + (lane >> 3);
  const int scol = (((lane & 7) ^ (lane >> 3)) << 3);
  const bf16* aPtr = A + (size_t)(m0 + srow) * K + scol;
  const bf16* bPtr = Bt + (size_t)(n0 + srow) * K + scol;
  bf16* ldsA = smem + wave * 2048;
  bf16* ldsB = smem + 8192 + wave * 2048;

  const int wr = (wave >> 1) * 64;
  const int wc = (wave & 1) * 64;
  const int lr = lane & 15;
  const int gl = lane >> 4;
  const int x7 = lr & 7;

  f32x4 acc[4][4] = {};

  for (int kt = 0; kt < K; kt += 64) {
#pragma unroll
    for (int j = 0; j < 4; j++) {
      GLOAD(aPtr + (size_t)(j * 8) * K + kt, ldsA + j * 512);
      GLOAD(bPtr + (size_t)(j * 8) * K + kt, ldsB + j * 512);
    }
    __syncthreads();
#pragma unroll
    for (int kk = 0; kk < 2; kk++) {
      const int og = ((kk * 4 + gl) ^ x7) << 3;
      bf16x8 af[4], bf[4];
#pragma unroll
      for (int i = 0; i < 4; i++)
        af[i] = *(const bf16x8*)(smem + (wr + i * 16 + lr) * 64 + og);
#pragma unroll
      for (int j = 0; j < 4; j++)
        bf[j] = *(const bf16x8*)(smem + 8192 + (wc + j * 16 + lr) * 64 + og);
#pragma unroll
      for (int i = 0; i < 4; i++)
#pragma unroll
        for (int j = 0; j < 4; j++)
          acc[i][j] = MFMA_(af[i], bf[j], acc[i][j], 0, 0, 0);
    }
    __syncthreads();
  }

  const int lr4 = (lane >> 4) << 2;
  const int lc = lane & 15;
  if (EPI == 0) {
    bf16* hs = smem;
#pragma unroll
    for (int j = 0; j < 4; j++) {
      int col = wc + j * 16 + lc;
      float bb = bias[n0 + col];
#pragma unroll
      for (int i = 0; i < 4; i++) {
#pragma unroll
        for (int q = 0; q < 4; q++) {
          int row = wr + i * 16 + lr4 + q;
          float v = acc[i][j][q] + bb;
          float u2 = 0.7978845608028654f * (v + 0.044715f * v * v * v);
          float th = 1.0f - 2.0f / (__expf(2.0f * u2) + 1.0f);
          hs[row * 128 + col] = __float2bfloat16(0.5f * v * (1.0f + th));
        }
      }
    }
    __syncthreads();
    bf16* h = (bf16*)outv;
#pragma unroll
    for (int it = 0; it < 8; it++) {
      int gr = tid + it * 256;
      int row = gr >> 4;
      int col = (gr & 15) * 8;
      *(bf16x8*)(h + (size_t)(m0 + row) * N + n0 + col) = *(const bf16x8*)(hs + gr * 8);
    }
  } else {
    float* o = (float*)outv;
    const float* res = isP ? (res1 + (size_t)m0 * N) : (res0 + (size_t)(m0 - MP) * N);
    float* fs = (float*)smem;
#pragma unroll
    for (int half = 0; half < 2; half++) {
      if ((wave >> 1) == half) {
#pragma unroll
        for (int j = 0; j < 4; j++) {
          int col = wc + j * 16 + lc;
          float bb = bias[n0 + col];
#pragma unroll
          for (int i = 0; i < 4; i++) {
#pragma unroll
            for (int q = 0; q < 4; q++) {
              int row = i * 16 + lr4 + q;
              fs[row * 128 + col] = acc[i][j][q] + bb;
            }
          }
        }
      }
      __syncthreads();
#pragma unroll
      for (int it = 0; it < 8; it++) {
        int gr = tid + it * 256;
        int row = gr >> 5;
        int col = (gr & 31) * 4;
        size_t goff = (size_t)(half * 64 + row) * N + n0 + col;
        float4 v = *(const float4*)(fs + gr * 4);
        float4 rr = *(const float4*)(res + goff);
        v.x += rr.x; v.y += rr.y; v.z += rr.z; v.w += rr.w;
        *(float4*)(o + (size_t)m0 * N + goff) = v;
      }
      __syncthreads();
    }
  }
}

// ---------------------------------------------------------------------------
extern "C" void kernel_launch(void* const* d_in, const int* in_sizes, int n_in,
                              void* d_out, int out_size, void* d_ws, size_t ws_size,
                              hipStream_t stream) {
  const float* p_h = (const float*)d_in[0];
  const float* l_h = (const float*)d_in[1];
  const float* ln_scale = (const float*)d_in[4];
  const float* ln_bias = (const float*)d_in[5];
  const float* w1 = (const float*)d_in[14];
  const float* b1 = (const float*)d_in[15];
  const float* w2 = (const float*)d_in[16];
  const float* b2 = (const float*)d_in[17];

  bf16* ws = (bf16*)d_ws;
  bf16* w1T = ws; ws += (size_t)2 * DFF * DIM;
  bf16* w2T = ws; ws += (size_t)2 * DIM * DFF;
  bf16* y = ws;   ws += (size_t)MT * DIM;
  bf16* h = ws;   ws += (size_t)MT * DFF;

  for (int s = 0; s < 2; s++) {
    transpose_cast<<<dim3(DFF / 32, DIM / 32), 256, 0, stream>>>(
        w1 + (size_t)s * DIM * DFF, w1T + (size_t)s * DFF * DIM, DIM, DFF);
    transpose_cast<<<dim3(DIM / 32, DFF / 32), 256, 0, stream>>>(
        w2 + (size_t)s * DFF * DIM, w2T + (size_t)s * DIM * DFF, DFF, DIM);
  }

  ln_rows<<<MP, 256, 0, stream>>>(p_h, ln_scale + 5 * DIM, ln_bias + 5 * DIM, y);
  ln_rows<<<ML, 256, 0, stream>>>(l_h, ln_scale + 4 * DIM, ln_bias + 4 * DIM,
                                  y + (size_t)MP * DIM);

  // GEMM1: h = gelu(y @ w1 + b1); 40x16 = 640 blocks, 256^2 8-phase
  gemm256<0><<<(MT / 256) * (DFF / 256), 512, 0, stream>>>(
      y, w1T, w1T + (size_t)DFF * DIM, b1, b1 + DFF, nullptr, nullptr,
      h, DFF, DIM, MT / 256);

  // GEMM2: out = resid + h @ w2 + b2; 640 blocks, 128^2 m97-style
  gemm97<1><<<(MT / 128) * (DIM / 128), 256, 0, stream>>>(
      h, w2T, w2T + (size_t)DIM * DFF, b2, b2 + DIM, l_h, p_h,
      (void*)d_out, DIM, DFF, DIM / 128);
}

// Round 9
// 260.226 us; speedup vs baseline: 1.0439x; 1.0439x over previous
//
#include <hip/hip_runtime.h>
#include <hip/hip_bf16.h>
#include <math.h>

// ---------------------------------------------------------------------------
// Reduction (proven r0): gated attention is identically zero => model ==
// two residual FFN blocks:
//   p_out = p_h + gelu(LN(p_h)@w1[1]+b1[1])@w2[1]+b2[1]
//   l_out = l_h + gelu(LN(l_h)@w1[0]+b1[0])@w2[0]+b2[0]
// r9: r7's proven TLP machine (128x128, BK=64, 4 waves, single 32KiB LDS,
// __syncthreads drain, 3 blocks/CU) with MFMA currency switched to
// 32x32x16 (516 vs 620 cyc/K-tile/CU; m119 ceiling 2495 vs 2075 TF).
// Same staging, same granule-XOR swizzle, same LDS-bounce epilogues.
// Prep fused: 1 LN launch (was 2), 1 transpose launch (was 4).
// ---------------------------------------------------------------------------

#define DIM 1024
#define DFF 4096
#define MP 8192
#define ML 2048
#define MT (MP + ML)  // 10240 rows, P first then L

typedef __bf16 bf16x8 __attribute__((ext_vector_type(8)));
typedef float f32x16 __attribute__((ext_vector_type(16)));
using bf16 = __hip_bfloat16;

// ---------------- fused transpose + cast for w1 and w2 ----------------------
// z<2: w1 stream z  [DIM][DFF] -> w1T[z][DFF][DIM]
// z>=2: w2 stream z-2 [DFF][DIM] -> w2T[z-2][DIM][DFF]
__global__ void transpose_all(const float* __restrict__ w1, const float* __restrict__ w2,
                              bf16* __restrict__ w1T, bf16* __restrict__ w2T) {
  __shared__ float tile[32][33];
  const int z = blockIdx.z;
  const float* in;
  bf16* out;
  int R, C, r0, c0;
  if (z < 2) {
    in = w1 + (size_t)z * DIM * DFF;
    out = w1T + (size_t)z * DFF * DIM;
    R = DIM; C = DFF;
    r0 = blockIdx.y * 32; c0 = blockIdx.x * 32;
  } else {
    in = w2 + (size_t)(z - 2) * DFF * DIM;
    out = w2T + (size_t)(z - 2) * DIM * DFF;
    R = DFF; C = DIM;
    r0 = blockIdx.x * 32; c0 = blockIdx.y * 32;
  }
  int tc = threadIdx.x & 31;
  int tr = threadIdx.x >> 5;
#pragma unroll
  for (int i = 0; i < 4; i++)
    tile[tr + i * 8][tc] = in[(size_t)(r0 + tr + i * 8) * C + c0 + tc];
  __syncthreads();
#pragma unroll
  for (int i = 0; i < 4; i++)
    out[(size_t)(c0 + tr + i * 8) * R + r0 + tc] = __float2bfloat16(tile[tc][tr + i * 8]);
}

// ---------------- fused LayerNorm: all MT rows in one launch ----------------
__global__ void ln_all(const float* __restrict__ p_h, const float* __restrict__ l_h,
                       const float* __restrict__ sc_all, const float* __restrict__ bi_all,
                       bf16* __restrict__ y) {
  int row = blockIdx.x;
  const float* x;
  const float* sc;
  const float* bi;
  if (row < MP) {           // protein rows -> LN set 5 (ffn_p)
    x = p_h + (size_t)row * DIM;
    sc = sc_all + 5 * DIM; bi = bi_all + 5 * DIM;
  } else {                  // ligand rows -> LN set 4 (ffn_l)
    x = l_h + (size_t)(row - MP) * DIM;
    sc = sc_all + 4 * DIM; bi = bi_all + 4 * DIM;
  }
  int t = threadIdx.x;
  float4 v = ((const float4*)x)[t];
  float s = v.x + v.y + v.z + v.w;
#pragma unroll
  for (int o = 32; o >= 1; o >>= 1) s += __shfl_down(s, o);
  __shared__ float red[8];
  int lane = t & 63, w = t >> 6;
  if (lane == 0) red[w] = s;
  __syncthreads();
  float mean = (red[0] + red[1] + red[2] + red[3]) * (1.0f / DIM);
  float dx = v.x - mean, dy = v.y - mean, dz = v.z - mean, dw = v.w - mean;
  float ss = dx * dx + dy * dy + dz * dz + dw * dw;
#pragma unroll
  for (int o = 32; o >= 1; o >>= 1) ss += __shfl_down(ss, o);
  if (lane == 0) red[4 + w] = ss;
  __syncthreads();
  float var = (red[4] + red[5] + red[6] + red[7]) * (1.0f / DIM);
  float rstd = rsqrtf(var + 1e-5f);
  float4 scv = ((const float4*)sc)[t];
  float4 biv = ((const float4*)bi)[t];
  bf16 o4[4];
  o4[0] = __float2bfloat16(dx * rstd * scv.x + biv.x);
  o4[1] = __float2bfloat16(dy * rstd * scv.y + biv.y);
  o4[2] = __float2bfloat16(dz * rstd * scv.z + biv.z);
  o4[3] = __float2bfloat16(dw * rstd * scv.w + biv.w);
  *(short4*)(y + (size_t)row * DIM + t * 4) = *(short4*)o4;
}

// ---------------- 128x128 BK=64 TLP GEMM, 32x32x16 MFMA ---------------------
// LDS: sA[128][64] + sB[128][64] bf16 = 32 KiB single buffer; granule-XOR
// swizzle phys_g = g ^ (row&7), staged linear with pre-swizzled global col
// (r7-proven). Wave owns 64x64 quadrant = 2x2 of 32x32 MFMA tiles.
// Per K-tile: 4 k16-steps x {2 A-frag + 2 B-frag ds_read_b128, 4 MFMA}.
// A/B frag (32x32x16): row/col = lane&31, k-granule(8) = lane>>5.
// C/D: col = lane&31, row = (reg&3) + 8*(reg>>2) + 4*(lane>>5).

#define GLOAD(gp, ldsElem)                                                          \
  __builtin_amdgcn_global_load_lds(                                                 \
      (const __attribute__((address_space(1))) void*)(gp),                          \
      (__attribute__((address_space(3))) void*)(ldsElem), 16, 0, 0)

template <int EPI>  // 0: gelu -> bf16 h ; 1: +bias +resid -> f32 out
__global__ __launch_bounds__(256, 3) void gemm97(
    const bf16* __restrict__ A, const bf16* __restrict__ B0, const bf16* __restrict__ B1,
    const float* __restrict__ bias0, const float* __restrict__ bias1,
    const float* __restrict__ res0, const float* __restrict__ res1,
    void* __restrict__ outv, int N, int K, int nCol) {
  __shared__ alignas(16) bf16 smem[16384];  // sA [0,8192) sB [8192,16384)
  const int tid = threadIdx.x;
  const int lane = tid & 63;
  const int wave = tid >> 6;  // 0..3

  const int nwg = gridDim.x;
  const int swz = (blockIdx.x & 7) * (nwg >> 3) + (blockIdx.x >> 3);
  const int m0 = (swz / nCol) << 7;
  const int n0 = (swz % nCol) << 7;

  const bool isP = (m0 < MP);
  const bf16* Bt = isP ? B1 : B0;
  const float* bias = isP ? bias1 : bias0;

  // staging (unchanged from r7): wave w, instr j covers rows w*32+j*8..+8
  const int srow = wave * 32 + (lane >> 3);
  const int scol = (((lane & 7) ^ (lane >> 3)) << 3);
  const bf16* aPtr = A + (size_t)(m0 + srow) * K + scol;
  const bf16* bPtr = Bt + (size_t)(n0 + srow) * K + scol;
  bf16* ldsA = smem + wave * 2048;
  bf16* ldsB = smem + 8192 + wave * 2048;

  // fragment geometry (32x32x16)
  const int wr = (wave >> 1) * 64;
  const int wc = (wave & 1) * 64;
  const int l31 = lane & 31;
  const int h5 = lane >> 5;      // k-granule 0..1 within k16
  const int x7 = l31 & 7;        // read-side row XOR

  f32x16 acc[2][2] = {};

  for (int kt = 0; kt < K; kt += 64) {
#pragma unroll
    for (int j = 0; j < 4; j++) {
      GLOAD(aPtr + (size_t)(j * 8) * K + kt, ldsA + j * 512);
      GLOAD(bPtr + (size_t)(j * 8) * K + kt, ldsB + j * 512);
    }
    __syncthreads();  // drains vmcnt+lgkmcnt: staged tile visible
#pragma unroll
    for (int kk = 0; kk < 4; kk++) {
      const int og = ((kk * 2 + h5) ^ x7) << 3;  // swizzled granule (elems)
      bf16x8 af[2], bf[2];
#pragma unroll
      for (int mt = 0; mt < 2; mt++)
        af[mt] = *(const bf16x8*)(smem + (wr + mt * 32 + l31) * 64 + og);
#pragma unroll
      for (int nt = 0; nt < 2; nt++)
        bf[nt] = *(const bf16x8*)(smem + 8192 + (wc + nt * 32 + l31) * 64 + og);
#pragma unroll
      for (int mt = 0; mt < 2; mt++)
#pragma unroll
        for (int nt = 0; nt < 2; nt++)
          acc[mt][nt] = __builtin_amdgcn_mfma_f32_32x32x16_bf16(
              af[mt], bf[nt], acc[mt][nt], 0, 0, 0);
    }
    __syncthreads();  // protect LDS before next stage
  }

  // epilogue. C/D: row = wr+mt*32+(reg&3)+8*(reg>>2)+4*h5, col = wc+nt*32+l31
  if (EPI == 0) {
    bf16* hs = smem;  // [128][128] bf16 = 32 KiB
#pragma unroll
    for (int nt = 0; nt < 2; nt++) {
      int col = wc + nt * 32 + l31;
      float bb = bias[n0 + col];
#pragma unroll
      for (int mt = 0; mt < 2; mt++) {
#pragma unroll
        for (int reg = 0; reg < 16; reg++) {
          int row = wr + mt * 32 + (reg & 3) + 8 * (reg >> 2) + 4 * h5;
          float v = acc[mt][nt][reg] + bb;
          float u2 = 0.7978845608028654f * (v + 0.044715f * v * v * v);
          float th = 1.0f - 2.0f / (__expf(2.0f * u2) + 1.0f);  // tanh
          hs[row * 128 + col] = __float2bfloat16(0.5f * v * (1.0f + th));
        }
      }
    }
    __syncthreads();
    bf16* h = (bf16*)outv;
#pragma unroll
    for (int it = 0; it < 8; it++) {
      int gr = tid + it * 256;       // granule of 8 bf16
      int row = gr >> 4;
      int col = (gr & 15) * 8;
      *(bf16x8*)(h + (size_t)(m0 + row) * N + n0 + col) = *(const bf16x8*)(hs + gr * 8);
    }
  } else {
    float* o = (float*)outv;
    const float* res = isP ? (res1 + (size_t)m0 * N) : (res0 + (size_t)(m0 - MP) * N);
    float* fs = (float*)smem;  // [64][128] f32 = 32 KiB per half-pass
#pragma unroll
    for (int half = 0; half < 2; half++) {
      if ((wave >> 1) == half) {  // waves owning rows [half*64, half*64+64)
#pragma unroll
        for (int nt = 0; nt < 2; nt++) {
          int col = wc + nt * 32 + l31;
          float bb = bias[n0 + col];
#pragma unroll
          for (int mt = 0; mt < 2; mt++) {
#pragma unroll
            for (int reg = 0; reg < 16; reg++) {
              int row = mt * 32 + (reg & 3) + 8 * (reg >> 2) + 4 * h5;  // 0..63
              fs[row * 128 + col] = acc[mt][nt][reg] + bb;
            }
          }
        }
      }
      __syncthreads();
#pragma unroll
      for (int it = 0; it < 8; it++) {
        int gr = tid + it * 256;     // granule of 4 f32
        int row = gr >> 5;
        int col = (gr & 31) * 4;
        size_t goff = (size_t)(half * 64 + row) * N + n0 + col;
        float4 v = *(const float4*)(fs + gr * 4);
        float4 rr = *(const float4*)(res + goff);
        v.x += rr.x; v.y += rr.y; v.z += rr.z; v.w += rr.w;
        *(float4*)(o + (size_t)m0 * N + goff) = v;
      }
      __syncthreads();
    }
  }
}

// ---------------------------------------------------------------------------
extern "C" void kernel_launch(void* const* d_in, const int* in_sizes, int n_in,
                              void* d_out, int out_size, void* d_ws, size_t ws_size,
                              hipStream_t stream) {
  const float* p_h = (const float*)d_in[0];
  const float* l_h = (const float*)d_in[1];
  const float* ln_scale = (const float*)d_in[4];
  const float* ln_bias = (const float*)d_in[5];
  const float* w1 = (const float*)d_in[14];
  const float* b1 = (const float*)d_in[15];
  const float* w2 = (const float*)d_in[16];
  const float* b2 = (const float*)d_in[17];

  // workspace (bf16): w1T[2][DFF][DIM], w2T[2][DIM][DFF], y[MT][DIM], h[MT][DFF]
  bf16* ws = (bf16*)d_ws;
  bf16* w1T = ws; ws += (size_t)2 * DFF * DIM;
  bf16* w2T = ws; ws += (size_t)2 * DIM * DFF;
  bf16* y = ws;   ws += (size_t)MT * DIM;
  bf16* h = ws;   ws += (size_t)MT * DFF;

  // prep: 1 transpose launch (both weights, both streams), 1 LN launch
  transpose_all<<<dim3(DFF / 32, DIM / 32, 4), 256, 0, stream>>>(w1, w2, w1T, w2T);
  ln_all<<<MT, 256, 0, stream>>>(p_h, l_h, ln_scale, ln_bias, y);

  // GEMM1: h = gelu(y @ w1 + b1); 80 x 32 = 2560 blocks (10 even rounds)
  gemm97<0><<<(MT / 128) * (DFF / 128), 256, 0, stream>>>(
      y, w1T, w1T + (size_t)DFF * DIM, b1, b1 + DFF, nullptr, nullptr,
      h, DFF, DIM, DFF / 128);

  // GEMM2: out = resid + h @ w2 + b2; 80 x 8 = 640 blocks
  gemm97<1><<<(MT / 128) * (DIM / 128), 256, 0, stream>>>(
      h, w2T, w2T + (size_t)DIM * DFF, b2, b2 + DIM, l_h, p_h,
      (void*)d_out, DIM, DFF, DIM / 128);
}

// Round 10
// 250.927 us; speedup vs baseline: 1.0826x; 1.0371x over previous
//
#include <hip/hip_runtime.h>
#include <hip/hip_bf16.h>
#include <math.h>

// ---------------------------------------------------------------------------
// Reduction (proven r0): gated attention is identically zero => model ==
// two residual FFN blocks:
//   p_out = p_h + gelu(LN(p_h)@w1[1]+b1[1])@w2[1]+b2[1]
//   l_out = l_h + gelu(LN(l_h)@w1[0]+b1[0])@w2[0]+b2[0]
// r10: r7's proven TLP machine EXACTLY (128x128, BK=64, 16x16x32 MFMA,
// single 32KiB LDS, __syncthreads drain, granule-XOR swizzle both-sides,
// LDS-bounce epilogues) with occupancy raised 3 -> 4 blocks/CU via
// __launch_bounds__(256,4) (reg budget 64+64=128 = exactly 4 waves/SIMD).
// r9's 32x32 currency reverted (bank-quad aliasing of rows r,r+8,r+16,r+24
// caused 8x conflicts). Fused prep (1 transpose + 1 LN launch) kept.
// ---------------------------------------------------------------------------

#define DIM 1024
#define DFF 4096
#define MP 8192
#define ML 2048
#define MT (MP + ML)  // 10240 rows, P first then L

typedef __bf16 bf16x8 __attribute__((ext_vector_type(8)));
typedef float f32x4 __attribute__((ext_vector_type(4)));
using bf16 = __hip_bfloat16;

// ---------------- fused transpose + cast for w1 and w2 ----------------------
__global__ void transpose_all(const float* __restrict__ w1, const float* __restrict__ w2,
                              bf16* __restrict__ w1T, bf16* __restrict__ w2T) {
  __shared__ float tile[32][33];
  const int z = blockIdx.z;
  const float* in;
  bf16* out;
  int R, C, r0, c0;
  if (z < 2) {
    in = w1 + (size_t)z * DIM * DFF;
    out = w1T + (size_t)z * DFF * DIM;
    R = DIM; C = DFF;
    r0 = blockIdx.y * 32; c0 = blockIdx.x * 32;
  } else {
    in = w2 + (size_t)(z - 2) * DFF * DIM;
    out = w2T + (size_t)(z - 2) * DIM * DFF;
    R = DFF; C = DIM;
    r0 = blockIdx.x * 32; c0 = blockIdx.y * 32;
  }
  int tc = threadIdx.x & 31;
  int tr = threadIdx.x >> 5;
#pragma unroll
  for (int i = 0; i < 4; i++)
    tile[tr + i * 8][tc] = in[(size_t)(r0 + tr + i * 8) * C + c0 + tc];
  __syncthreads();
#pragma unroll
  for (int i = 0; i < 4; i++)
    out[(size_t)(c0 + tr + i * 8) * R + r0 + tc] = __float2bfloat16(tile[tc][tr + i * 8]);
}

// ---------------- fused LayerNorm: all MT rows in one launch ----------------
__global__ void ln_all(const float* __restrict__ p_h, const float* __restrict__ l_h,
                       const float* __restrict__ sc_all, const float* __restrict__ bi_all,
                       bf16* __restrict__ y) {
  int row = blockIdx.x;
  const float* x;
  const float* sc;
  const float* bi;
  if (row < MP) {           // protein rows -> LN set 5 (ffn_p)
    x = p_h + (size_t)row * DIM;
    sc = sc_all + 5 * DIM; bi = bi_all + 5 * DIM;
  } else {                  // ligand rows -> LN set 4 (ffn_l)
    x = l_h + (size_t)(row - MP) * DIM;
    sc = sc_all + 4 * DIM; bi = bi_all + 4 * DIM;
  }
  int t = threadIdx.x;
  float4 v = ((const float4*)x)[t];
  float s = v.x + v.y + v.z + v.w;
#pragma unroll
  for (int o = 32; o >= 1; o >>= 1) s += __shfl_down(s, o);
  __shared__ float red[8];
  int lane = t & 63, w = t >> 6;
  if (lane == 0) red[w] = s;
  __syncthreads();
  float mean = (red[0] + red[1] + red[2] + red[3]) * (1.0f / DIM);
  float dx = v.x - mean, dy = v.y - mean, dz = v.z - mean, dw = v.w - mean;
  float ss = dx * dx + dy * dy + dz * dz + dw * dw;
#pragma unroll
  for (int o = 32; o >= 1; o >>= 1) ss += __shfl_down(ss, o);
  if (lane == 0) red[4 + w] = ss;
  __syncthreads();
  float var = (red[4] + red[5] + red[6] + red[7]) * (1.0f / DIM);
  float rstd = rsqrtf(var + 1e-5f);
  float4 scv = ((const float4*)sc)[t];
  float4 biv = ((const float4*)bi)[t];
  bf16 o4[4];
  o4[0] = __float2bfloat16(dx * rstd * scv.x + biv.x);
  o4[1] = __float2bfloat16(dy * rstd * scv.y + biv.y);
  o4[2] = __float2bfloat16(dz * rstd * scv.z + biv.z);
  o4[3] = __float2bfloat16(dw * rstd * scv.w + biv.w);
  *(short4*)(y + (size_t)row * DIM + t * 4) = *(short4*)o4;
}

// ---------------- 128x128 BK=64 TLP GEMM (r7-proven, 16x16x32) --------------
#define GLOAD(gp, ldsElem)                                                          \
  __builtin_amdgcn_global_load_lds(                                                 \
      (const __attribute__((address_space(1))) void*)(gp),                          \
      (__attribute__((address_space(3))) void*)(ldsElem), 16, 0, 0)

template <int EPI>  // 0: gelu -> bf16 h ; 1: +bias +resid -> f32 out
__global__ __launch_bounds__(256, 4) void gemm97(
    const bf16* __restrict__ A, const bf16* __restrict__ B0, const bf16* __restrict__ B1,
    const float* __restrict__ bias0, const float* __restrict__ bias1,
    const float* __restrict__ res0, const float* __restrict__ res1,
    void* __restrict__ outv, int N, int K, int nCol) {
  __shared__ alignas(16) bf16 smem[16384];  // sA [0,8192) sB [8192,16384)
  const int tid = threadIdx.x;
  const int lane = tid & 63;
  const int wave = tid >> 6;  // 0..3

  const int nwg = gridDim.x;
  const int swz = (blockIdx.x & 7) * (nwg >> 3) + (blockIdx.x >> 3);
  const int m0 = (swz / nCol) << 7;
  const int n0 = (swz % nCol) << 7;

  const bool isP = (m0 < MP);
  const bf16* Bt = isP ? B1 : B0;
  const float* bias = isP ? bias1 : bias0;

  // staging: wave w instr j covers rows w*32+j*8+(lane>>3); granule
  // pre-swizzled into global col: logical g = (lane&7) ^ (row&7)
  const int srow = wave * 32 + (lane >> 3);
  const int scol = (((lane & 7) ^ (lane >> 3)) << 3);
  const bf16* aPtr = A + (size_t)(m0 + srow) * K + scol;
  const bf16* bPtr = Bt + (size_t)(n0 + srow) * K + scol;
  bf16* ldsA = smem + wave * 2048;
  bf16* ldsB = smem + 8192 + wave * 2048;

  // fragment geometry (16x16x32)
  const int wr = (wave >> 1) * 64;
  const int wc = (wave & 1) * 64;
  const int lr = lane & 15;
  const int gl = lane >> 4;      // k-granule 0..3 within 32-k chunk
  const int x7 = lr & 7;         // read-side row XOR

  f32x4 acc[4][4] = {};

  for (int kt = 0; kt < K; kt += 64) {
#pragma unroll
    for (int j = 0; j < 4; j++) {
      GLOAD(aPtr + (size_t)(j * 8) * K + kt, ldsA + j * 512);
      GLOAD(bPtr + (size_t)(j * 8) * K + kt, ldsB + j * 512);
    }
    __syncthreads();  // drains vmcnt+lgkmcnt: staged tile visible
#pragma unroll
    for (int kk = 0; kk < 2; kk++) {
      const int og = ((kk * 4 + gl) ^ x7) << 3;  // swizzled k-offset (elems)
      bf16x8 af[4], bf[4];
#pragma unroll
      for (int i = 0; i < 4; i++)
        af[i] = *(const bf16x8*)(smem + (wr + i * 16 + lr) * 64 + og);
#pragma unroll
      for (int j = 0; j < 4; j++)
        bf[j] = *(const bf16x8*)(smem + 8192 + (wc + j * 16 + lr) * 64 + og);
#pragma unroll
      for (int i = 0; i < 4; i++)
#pragma unroll
        for (int j = 0; j < 4; j++)
          acc[i][j] = __builtin_amdgcn_mfma_f32_16x16x32_bf16(af[i], bf[j], acc[i][j], 0, 0, 0);
    }
    __syncthreads();  // protect LDS before next stage
  }

  // epilogue. C/D: row = wr + i*16 + (lane>>4)*4 + q ; col = wc + j*16 + (lane&15)
  const int lr4 = (lane >> 4) << 2;
  const int lc = lane & 15;
  if (EPI == 0) {
    bf16* hs = smem;  // [128][128] bf16 = 32 KiB
#pragma unroll
    for (int j = 0; j < 4; j++) {
      int col = wc + j * 16 + lc;
      float bb = bias[n0 + col];
#pragma unroll
      for (int i = 0; i < 4; i++) {
#pragma unroll
        for (int q = 0; q < 4; q++) {
          int row = wr + i * 16 + lr4 + q;
          float v = acc[i][j][q] + bb;
          float u2 = 0.7978845608028654f * (v + 0.044715f * v * v * v);
          float th = 1.0f - 2.0f / (__expf(2.0f * u2) + 1.0f);  // tanh
          hs[row * 128 + col] = __float2bfloat16(0.5f * v * (1.0f + th));
        }
      }
    }
    __syncthreads();
    bf16* h = (bf16*)outv;
#pragma unroll
    for (int it = 0; it < 8; it++) {
      int gr = tid + it * 256;       // granule of 8 bf16
      int row = gr >> 4;
      int col = (gr & 15) * 8;
      *(bf16x8*)(h + (size_t)(m0 + row) * N + n0 + col) = *(const bf16x8*)(hs + gr * 8);
    }
  } else {
    float* o = (float*)outv;
    const float* res = isP ? (res1 + (size_t)m0 * N) : (res0 + (size_t)(m0 - MP) * N);
    float* fs = (float*)smem;  // [64][128] f32 = 32 KiB per half-pass
#pragma unroll
    for (int half = 0; half < 2; half++) {
      if ((wave >> 1) == half) {  // waves owning rows [half*64, half*64+64)
#pragma unroll
        for (int j = 0; j < 4; j++) {
          int col = wc + j * 16 + lc;
          float bb = bias[n0 + col];
#pragma unroll
          for (int i = 0; i < 4; i++) {
#pragma unroll
            for (int q = 0; q < 4; q++) {
              int row = i * 16 + lr4 + q;  // 0..63 within half
              fs[row * 128 + col] = acc[i][j][q] + bb;
            }
          }
        }
      }
      __syncthreads();
#pragma unroll
      for (int it = 0; it < 8; it++) {
        int gr = tid + it * 256;     // granule of 4 f32
        int row = gr >> 5;
        int col = (gr & 31) * 4;
        size_t goff = (size_t)(half * 64 + row) * N + n0 + col;
        float4 v = *(const float4*)(fs + gr * 4);
        float4 rr = *(const float4*)(res + goff);
        v.x += rr.x; v.y += rr.y; v.z += rr.z; v.w += rr.w;
        *(float4*)(o + (size_t)m0 * N + goff) = v;
      }
      __syncthreads();
    }
  }
}

// ---------------------------------------------------------------------------
extern "C" void kernel_launch(void* const* d_in, const int* in_sizes, int n_in,
                              void* d_out, int out_size, void* d_ws, size_t ws_size,
                              hipStream_t stream) {
  const float* p_h = (const float*)d_in[0];
  const float* l_h = (const float*)d_in[1];
  const float* ln_scale = (const float*)d_in[4];
  const float* ln_bias = (const float*)d_in[5];
  const float* w1 = (const float*)d_in[14];
  const float* b1 = (const float*)d_in[15];
  const float* w2 = (const float*)d_in[16];
  const float* b2 = (const float*)d_in[17];

  // workspace (bf16): w1T[2][DFF][DIM], w2T[2][DIM][DFF], y[MT][DIM], h[MT][DFF]
  bf16* ws = (bf16*)d_ws;
  bf16* w1T = ws; ws += (size_t)2 * DFF * DIM;
  bf16* w2T = ws; ws += (size_t)2 * DIM * DFF;
  bf16* y = ws;   ws += (size_t)MT * DIM;
  bf16* h = ws;   ws += (size_t)MT * DFF;

  // prep: 1 transpose launch (both weights, both streams), 1 LN launch
  transpose_all<<<dim3(DFF / 32, DIM / 32, 4), 256, 0, stream>>>(w1, w2, w1T, w2T);
  ln_all<<<MT, 256, 0, stream>>>(p_h, l_h, ln_scale, ln_bias, y);

  // GEMM1: h = gelu(y @ w1 + b1); 80 x 32 = 2560 blocks (10 even rounds)
  gemm97<0><<<(MT / 128) * (DFF / 128), 256, 0, stream>>>(
      y, w1T, w1T + (size_t)DFF * DIM, b1, b1 + DFF, nullptr, nullptr,
      h, DFF, DIM, DFF / 128);

  // GEMM2: out = resid + h @ w2 + b2; 80 x 8 = 640 blocks
  gemm97<1><<<(MT / 128) * (DIM / 128), 256, 0, stream>>>(
      h, w2T, w2T + (size_t)DIM * DFF, b2, b2 + DIM, l_h, p_h,
      (void*)d_out, DIM, DFF, DIM / 128);
}